// Round 1
// baseline (236.408 us; speedup 1.0000x reference)
//
#include <hip/hip_runtime.h>
#include <hip/hip_bf16.h>

#define NE 1024       // N_EMBD
#define NH 16         // N_HEAD
#define HD 64         // HEAD_SIZE
#define TSEQ 2048
#define BATCH 2

typedef __attribute__((ext_vector_type(8))) short bf16x8;
typedef __attribute__((ext_vector_type(4))) float f32x4;
typedef unsigned short u16;

__device__ inline u16 f2bf(float f) {
    __hip_bfloat16 h = __float2bfloat16(f);
    return *reinterpret_cast<u16*>(&h);
}

#define GLD16(gptr, lptr)                                                        \
    __builtin_amdgcn_global_load_lds(                                            \
        (const __attribute__((address_space(1))) void*)(gptr),                   \
        (__attribute__((address_space(3))) void*)(lptr), 16, 0, 0)

// ---------- elementwise f32 -> bf16 ----------
__global__ void k_f32_to_bf16(const float* __restrict__ in, u16* __restrict__ out, int n4) {
    int i = blockIdx.x * blockDim.x + threadIdx.x;
    int stride = gridDim.x * blockDim.x;
    for (; i < n4; i += stride) {
        float4 v = reinterpret_cast<const float4*>(in)[i];
        ushort4 o;
        o.x = f2bf(v.x); o.y = f2bf(v.y); o.z = f2bf(v.z); o.w = f2bf(v.w);
        reinterpret_cast<ushort4*>(out)[i] = o;
    }
}

// ---------- transpose + convert: in [K][N] f32 -> out [N][K] bf16 ----------
__global__ void k_transpose_bf16(const float* __restrict__ in, u16* __restrict__ out,
                                 int K, int N) {
    __shared__ float tile[32][33];
    int bn = blockIdx.x * 32;
    int bk = blockIdx.y * 32;
    int tx = threadIdx.x, ty = threadIdx.y;
#pragma unroll
    for (int i = 0; i < 32; i += 8)
        tile[ty + i][tx] = in[(size_t)(bk + ty + i) * N + bn + tx];
    __syncthreads();
#pragma unroll
    for (int i = 0; i < 32; i += 8)
        out[(size_t)(bn + ty + i) * K + bk + tx] = f2bf(tile[tx][ty + i]);
}

// ---------- GEMM: C[M,N] = A[M,K] * Bt[N,K]^T + bias ----------
// MODE 0: scatter to q/k/v [B,H,T,D] bf16   MODE 1: plain f32 out
template <int MODE>
__global__ __launch_bounds__(256, 2) void k_gemm_bt(
    const u16* __restrict__ A, const u16* __restrict__ Bt,
    const float* __restrict__ bias, void* __restrict__ outp,
    int M, int N, int K) {
    __shared__ __align__(16) u16 As[128 * 32];
    __shared__ __align__(16) u16 Bs[128 * 32];
    const int l = threadIdx.x & 63;
    const int w = threadIdx.x >> 6;
    const int m0 = blockIdx.x * 128;
    const int n0 = blockIdx.y * 128;
    const int wr = w >> 1, wc = w & 1;

    f32x4 acc[4][4] = {};
    const int nkt = K >> 5;
    for (int kt = 0; kt < nkt; ++kt) {
        __syncthreads();
#pragma unroll
        for (int i = 0; i < 2; ++i) {
            int c = w * 2 + i;
            const u16* gA = A + (size_t)(m0 + c * 16 + (l >> 2)) * K + (kt << 5) + (l & 3) * 8;
            const u16* gB = Bt + (size_t)(n0 + c * 16 + (l >> 2)) * K + (kt << 5) + (l & 3) * 8;
            GLD16(gA, As + c * 512);
            GLD16(gB, Bs + c * 512);
        }
        __syncthreads();
        bf16x8 af[4], bfr[4];
#pragma unroll
        for (int mi = 0; mi < 4; ++mi)
            af[mi] = *reinterpret_cast<const bf16x8*>(As + (wr * 64 + mi * 16 + (l & 15)) * 32 + (l >> 4) * 8);
#pragma unroll
        for (int ni = 0; ni < 4; ++ni)
            bfr[ni] = *reinterpret_cast<const bf16x8*>(Bs + (wc * 64 + ni * 16 + (l & 15)) * 32 + (l >> 4) * 8);
#pragma unroll
        for (int mi = 0; mi < 4; ++mi)
#pragma unroll
            for (int ni = 0; ni < 4; ++ni)
                acc[mi][ni] = __builtin_amdgcn_mfma_f32_16x16x32_bf16(af[mi], bfr[ni], acc[mi][ni], 0, 0, 0);
    }

    if (MODE == 1) {
        float* C = (float*)outp;
#pragma unroll
        for (int mi = 0; mi < 4; ++mi)
#pragma unroll
            for (int ni = 0; ni < 4; ++ni) {
                int n = n0 + wc * 64 + ni * 16 + (l & 15);
                float bv = bias[n];
#pragma unroll
                for (int r = 0; r < 4; ++r) {
                    int m = m0 + wr * 64 + mi * 16 + (l >> 4) * 4 + r;
                    C[(size_t)m * N + n] = acc[mi][ni][r] + bv;
                }
            }
    } else {
        u16* qkv = (u16*)outp;  // q, k, v each BATCH*NH*TSEQ*HD, contiguous
#pragma unroll
        for (int mi = 0; mi < 4; ++mi)
#pragma unroll
            for (int ni = 0; ni < 4; ++ni) {
                int n = n0 + wc * 64 + ni * 16 + (l & 15);
                float bv = bias[n];
                int which = n >> 10;
                int c = n & 1023;
                int h = c >> 6, d = c & 63;
#pragma unroll
                for (int r = 0; r < 4; ++r) {
                    int m = m0 + wr * 64 + mi * 16 + (l >> 4) * 4 + r;
                    int b = m >> 11, t = m & 2047;
                    float v = acc[mi][ni][r] + bv;
                    size_t dst = (size_t)which * (BATCH * NH * TSEQ * HD) +
                                 (((size_t)(b * NH + h) * TSEQ + t) * HD) + d;
                    qkv[dst] = f2bf(v);
                }
            }
    }
}

// ---------- causal flash attention ----------
// grid: (TSEQ/64, BATCH*NH), block 256 (4 waves). Each block: 64 q-rows.
__global__ __launch_bounds__(256, 2) void k_attn(
    const u16* __restrict__ qb, const u16* __restrict__ kb, const u16* __restrict__ vb,
    u16* __restrict__ attn_out) {
    __shared__ __align__(16) u16 Ks[64 * 64];
    __shared__ __align__(16) u16 Vt[64 * 64];
    __shared__ __align__(16) u16 Ps[4][16 * 64];
    const int l = threadIdx.x & 63;
    const int w = threadIdx.x >> 6;
    const int q0 = blockIdx.x * 64;
    const int bh = blockIdx.y;
    const int b = bh >> 4, h = bh & 15;
    const size_t base = (size_t)bh * TSEQ * HD;
    const u16* Q = qb + base;
    const u16* Kg = kb + base;
    const u16* Vg = vb + base;

    const int qrow = q0 + w * 16 + (l & 15);
    bf16x8 qa[2];
    qa[0] = *reinterpret_cast<const bf16x8*>(Q + (size_t)qrow * HD + (l >> 4) * 8);
    qa[1] = *reinterpret_cast<const bf16x8*>(Q + (size_t)qrow * HD + 32 + (l >> 4) * 8);

    float mrow[4], lrow[4];
    f32x4 o[4] = {};
#pragma unroll
    for (int r = 0; r < 4; ++r) { mrow[r] = -1e30f; lrow[r] = 0.f; }

    const int ntiles = (q0 >> 6) + 1;
    for (int kt = 0; kt < ntiles; ++kt) {
        __syncthreads();
        // stage K (8KB contiguous) via global_load_lds
#pragma unroll
        for (int i = 0; i < 2; ++i) {
            int c = w * 2 + i;
            const u16* gK = Kg + (size_t)kt * 64 * HD + c * 512 + l * 8;
            GLD16(gK, Ks + c * 512);
        }
        // stage V transposed: Vt[d][k]
        {
            int t = threadIdx.x;
            int vrow = t >> 2;
            int dseg = (t & 3) * 16;
            const u16* gV = Vg + (size_t)(kt * 64 + vrow) * HD + dseg;
            bf16x8 v0 = *reinterpret_cast<const bf16x8*>(gV);
            bf16x8 v1 = *reinterpret_cast<const bf16x8*>(gV + 8);
#pragma unroll
            for (int j = 0; j < 8; ++j) {
                Vt[(dseg + j) * 64 + vrow] = (u16)v0[j];
                Vt[(dseg + 8 + j) * 64 + vrow] = (u16)v1[j];
            }
        }
        __syncthreads();
        // S = Q K^T  (16 q-rows per wave x 64 k-cols)
        f32x4 s[4] = {};
#pragma unroll
        for (int f = 0; f < 4; ++f)
#pragma unroll
            for (int ks = 0; ks < 2; ++ks) {
                bf16x8 bk = *reinterpret_cast<const bf16x8*>(Ks + (f * 16 + (l & 15)) * 64 + ks * 32 + (l >> 4) * 8);
                s[f] = __builtin_amdgcn_mfma_f32_16x16x32_bf16(qa[ks], bk, s[f], 0, 0, 0);
            }
        const bool diag = (kt == ntiles - 1);
        float p[4][4];
#pragma unroll
        for (int f = 0; f < 4; ++f)
#pragma unroll
            for (int r = 0; r < 4; ++r) {
                float sv = s[f][r] * 0.125f;
                if (diag) {
                    int kg = (kt << 6) + f * 16 + (l & 15);
                    int qg = q0 + w * 16 + (l >> 4) * 4 + r;
                    if (kg > qg) sv = -1e30f;
                }
                p[f][r] = sv;
            }
        // online softmax per q-row (reduce over 16-lane group)
#pragma unroll
        for (int r = 0; r < 4; ++r) {
            float rmax = fmaxf(fmaxf(p[0][r], p[1][r]), fmaxf(p[2][r], p[3][r]));
#pragma unroll
            for (int msk = 8; msk; msk >>= 1)
                rmax = fmaxf(rmax, __shfl_xor(rmax, msk));
            float mnew = fmaxf(mrow[r], rmax);
            float alpha = __expf(mrow[r] - mnew);
            mrow[r] = mnew;
            float rsum = 0.f;
#pragma unroll
            for (int f = 0; f < 4; ++f) {
                float pe = __expf(p[f][r] - mnew);
                p[f][r] = pe;
                rsum += pe;
            }
#pragma unroll
            for (int msk = 8; msk; msk >>= 1)
                rsum += __shfl_xor(rsum, msk);
            lrow[r] = lrow[r] * alpha + rsum;
#pragma unroll
            for (int nf = 0; nf < 4; ++nf)
                o[nf][r] *= alpha;
        }
        // P -> LDS (per-wave private region)
#pragma unroll
        for (int f = 0; f < 4; ++f)
#pragma unroll
            for (int r = 0; r < 4; ++r)
                Ps[w][((l >> 4) * 4 + r) * 64 + f * 16 + (l & 15)] = f2bf(p[f][r]);
        __syncthreads();
        // O += P V
#pragma unroll
        for (int nf = 0; nf < 4; ++nf)
#pragma unroll
            for (int ks = 0; ks < 2; ++ks) {
                bf16x8 pa = *reinterpret_cast<const bf16x8*>(&Ps[w][(l & 15) * 64 + ks * 32 + (l >> 4) * 8]);
                bf16x8 bv = *reinterpret_cast<const bf16x8*>(Vt + (nf * 16 + (l & 15)) * 64 + ks * 32 + (l >> 4) * 8);
                o[nf] = __builtin_amdgcn_mfma_f32_16x16x32_bf16(pa, bv, o[nf], 0, 0, 0);
            }
    }
    // epilogue: attn_out[b*T+q][h*64+d] bf16
#pragma unroll
    for (int nf = 0; nf < 4; ++nf)
#pragma unroll
        for (int r = 0; r < 4; ++r) {
            int q = q0 + w * 16 + (l >> 4) * 4 + r;
            int d = nf * 16 + (l & 15);
            float val = o[nf][r] / lrow[r];
            attn_out[(size_t)(b * TSEQ + q) * NE + h * HD + d] = f2bf(val);
        }
}

extern "C" void kernel_launch(void* const* d_in, const int* in_sizes, int n_in,
                              void* d_out, int out_size, void* d_ws, size_t ws_size,
                              hipStream_t stream) {
    const float* x = (const float*)d_in[0];
    const float* W_attn = (const float*)d_in[1];
    const float* b_attn = (const float*)d_in[2];
    const float* W_proj = (const float*)d_in[3];
    const float* b_proj = (const float*)d_in[4];
    float* out = (float*)d_out;

    char* ws = (char*)d_ws;
    u16* xb   = (u16*)(ws);                          // [4096,1024] bf16, 8MB
    u16* WaT  = (u16*)(ws + 8u * 1024 * 1024);       // [3072,1024] bf16, 6MB
    u16* WpT  = (u16*)(ws + 14u * 1024 * 1024);      // [1024,1024] bf16, 2MB
    u16* qkvb = (u16*)(ws + 16u * 1024 * 1024);      // 3 x [B,H,T,D] bf16, 24MB
    u16* attn = (u16*)(ws + 40u * 1024 * 1024);      // [4096,1024] bf16, 8MB

    const int M = BATCH * TSEQ;  // 4096

    k_f32_to_bf16<<<2048, 256, 0, stream>>>(x, xb, (M * NE) / 4);
    k_transpose_bf16<<<dim3(3 * NE / 32, NE / 32), dim3(32, 8), 0, stream>>>(W_attn, WaT, NE, 3 * NE);
    k_transpose_bf16<<<dim3(NE / 32, NE / 32), dim3(32, 8), 0, stream>>>(W_proj, WpT, NE, NE);

    k_gemm_bt<0><<<dim3(M / 128, (3 * NE) / 128), 256, 0, stream>>>(xb, WaT, b_attn, qkvb, M, 3 * NE, NE);

    const size_t headsz = (size_t)BATCH * NH * TSEQ * HD;  // 4M elems
    k_attn<<<dim3(TSEQ / 64, BATCH * NH), 256, 0, stream>>>(qkvb, qkvb + headsz, qkvb + 2 * headsz, attn);

    k_gemm_bt<1><<<dim3(M / 128, NE / 128), 256, 0, stream>>>(attn, WpT, b_proj, out, M, NE, NE);
}

// Round 2
// 190.802 us; speedup vs baseline: 1.2390x; 1.2390x over previous
//
#include <hip/hip_runtime.h>
#include <hip/hip_bf16.h>

#define NE 1024       // N_EMBD
#define NH 16         // N_HEAD
#define HD 64         // HEAD_SIZE
#define TSEQ 2048
#define BATCH 2

typedef __attribute__((ext_vector_type(8))) short bf16x8;
typedef __attribute__((ext_vector_type(4))) float f32x4;
typedef unsigned short u16;

__device__ inline u16 f2bf(float f) {
    __hip_bfloat16 h = __float2bfloat16(f);
    return *reinterpret_cast<u16*>(&h);
}

#define GLD16(gptr, lptr)                                                        \
    __builtin_amdgcn_global_load_lds(                                            \
        (const __attribute__((address_space(1))) void*)(gptr),                   \
        (__attribute__((address_space(3))) void*)(lptr), 16, 0, 0)

// ---------- elementwise f32 -> bf16 ----------
__global__ void k_f32_to_bf16(const float* __restrict__ in, u16* __restrict__ out, int n4) {
    int i = blockIdx.x * blockDim.x + threadIdx.x;
    int stride = gridDim.x * blockDim.x;
    for (; i < n4; i += stride) {
        float4 v = reinterpret_cast<const float4*>(in)[i];
        ushort4 o;
        o.x = f2bf(v.x); o.y = f2bf(v.y); o.z = f2bf(v.z); o.w = f2bf(v.w);
        reinterpret_cast<ushort4*>(out)[i] = o;
    }
}

// ---------- transpose + convert: in [K][N] f32 -> out [N][K] bf16 ----------
__global__ void k_transpose_bf16(const float* __restrict__ in, u16* __restrict__ out,
                                 int K, int N) {
    __shared__ float tile[32][33];
    int bn = blockIdx.x * 32;
    int bk = blockIdx.y * 32;
    int tx = threadIdx.x, ty = threadIdx.y;
#pragma unroll
    for (int i = 0; i < 32; i += 8)
        tile[ty + i][tx] = in[(size_t)(bk + ty + i) * N + bn + tx];
    __syncthreads();
#pragma unroll
    for (int i = 0; i < 32; i += 8)
        out[(size_t)(bn + ty + i) * K + bk + tx] = f2bf(tile[tx][ty + i]);
}

// ---------- GEMM: C[M,N] = A[M,K] * Bt[N,K]^T + bias ----------
// MODE 0: scatter q/k -> [B,H,T,D] bf16, v -> [B,H,D,T] bf16 (transposed)
// MODE 1: plain f32 out
template <int MODE>
__global__ __launch_bounds__(256, 2) void k_gemm_bt(
    const u16* __restrict__ A, const u16* __restrict__ Bt,
    const float* __restrict__ bias, void* __restrict__ outp,
    int M, int N, int K) {
    __shared__ __align__(16) u16 As[128 * 32];
    __shared__ __align__(16) u16 Bs[128 * 32];
    const int l = threadIdx.x & 63;
    const int w = threadIdx.x >> 6;
    const int m0 = blockIdx.x * 128;
    const int n0 = blockIdx.y * 128;
    const int wr = w >> 1, wc = w & 1;

    f32x4 acc[4][4] = {};
    const int nkt = K >> 5;
    for (int kt = 0; kt < nkt; ++kt) {
        __syncthreads();
#pragma unroll
        for (int i = 0; i < 2; ++i) {
            int c = w * 2 + i;
            const u16* gA = A + (size_t)(m0 + c * 16 + (l >> 2)) * K + (kt << 5) + (l & 3) * 8;
            const u16* gB = Bt + (size_t)(n0 + c * 16 + (l >> 2)) * K + (kt << 5) + (l & 3) * 8;
            GLD16(gA, As + c * 512);
            GLD16(gB, Bs + c * 512);
        }
        __syncthreads();
        bf16x8 af[4], bfr[4];
#pragma unroll
        for (int mi = 0; mi < 4; ++mi)
            af[mi] = *reinterpret_cast<const bf16x8*>(As + (wr * 64 + mi * 16 + (l & 15)) * 32 + (l >> 4) * 8);
#pragma unroll
        for (int ni = 0; ni < 4; ++ni)
            bfr[ni] = *reinterpret_cast<const bf16x8*>(Bs + (wc * 64 + ni * 16 + (l & 15)) * 32 + (l >> 4) * 8);
#pragma unroll
        for (int mi = 0; mi < 4; ++mi)
#pragma unroll
            for (int ni = 0; ni < 4; ++ni)
                acc[mi][ni] = __builtin_amdgcn_mfma_f32_16x16x32_bf16(af[mi], bfr[ni], acc[mi][ni], 0, 0, 0);
    }

    if (MODE == 1) {
        float* C = (float*)outp;
#pragma unroll
        for (int mi = 0; mi < 4; ++mi)
#pragma unroll
            for (int ni = 0; ni < 4; ++ni) {
                int n = n0 + wc * 64 + ni * 16 + (l & 15);
                float bv = bias[n];
#pragma unroll
                for (int r = 0; r < 4; ++r) {
                    int m = m0 + wr * 64 + mi * 16 + (l >> 4) * 4 + r;
                    C[(size_t)m * N + n] = acc[mi][ni][r] + bv;
                }
            }
    } else {
        u16* qkv = (u16*)outp;
        const size_t headsz = (size_t)BATCH * NH * TSEQ * HD;
#pragma unroll
        for (int mi = 0; mi < 4; ++mi)
#pragma unroll
            for (int ni = 0; ni < 4; ++ni) {
                int n = n0 + wc * 64 + ni * 16 + (l & 15);
                float bv = bias[n];
                int which = n >> 10;
                int c = n & 1023;
                int h = c >> 6, d = c & 63;
#pragma unroll
                for (int r = 0; r < 4; ++r) {
                    int m = m0 + wr * 64 + mi * 16 + (l >> 4) * 4 + r;
                    int b = m >> 11, t = m & 2047;
                    float v = acc[mi][ni][r] + bv;
                    size_t dst;
                    if (which == 2)  // V stored transposed: [B,H,D,T]
                        dst = 2 * headsz + ((size_t)(b * NH + h) * HD + d) * TSEQ + t;
                    else
                        dst = (size_t)which * headsz + ((size_t)(b * NH + h) * TSEQ + t) * HD + d;
                    qkv[dst] = f2bf(v);
                }
            }
    }
}

// ---------- causal flash attention ----------
// grid: (TSEQ/64, BATCH*NH), block 256 (4 waves). Each block: 64 q-rows.
// K staged [64k][64d], V^T staged [64d][64k]; both XOR-chunk-swizzled, double-buffered.
__global__ __launch_bounds__(256, 2) void k_attn(
    const u16* __restrict__ qb, const u16* __restrict__ kb, const u16* __restrict__ vtb,
    u16* __restrict__ attn_out) {
    __shared__ __align__(16) u16 Ks[2][64 * 64];
    __shared__ __align__(16) u16 Vs[2][64 * 64];
    __shared__ __align__(16) u16 Ps[4][16 * 64];
    const int l = threadIdx.x & 63;
    const int w = threadIdx.x >> 6;
    const int g = l >> 4, l15 = l & 15;
    const int nqt = gridDim.x;
    const int q0 = (nqt - 1 - (int)blockIdx.x) * 64;  // heavy tiles first
    const int bh = blockIdx.y;
    const int b = bh >> 4, h = bh & 15;
    const size_t base = (size_t)bh * TSEQ * HD;
    const u16* Q = qb + base;
    const u16* Kg = kb + base;
    const u16* Vg = vtb + base;  // [64 d][2048 t]

    // staging lane decomposition: 8 rows x 8 chunks of 8 elems per 1KB call
    const int lrow8 = l >> 3;                 // row within call, 0..7
    const int lchunk = (l & 7) ^ lrow8;       // inverse-swizzled source chunk

    const int qrow = q0 + w * 16 + l15;
    bf16x8 qa[2];
    qa[0] = *reinterpret_cast<const bf16x8*>(Q + (size_t)qrow * HD + g * 8);
    qa[1] = *reinterpret_cast<const bf16x8*>(Q + (size_t)qrow * HD + 32 + g * 8);

    float mrow[4], lsum[4];
    f32x4 o[4] = {};
#pragma unroll
    for (int r = 0; r < 4; ++r) { mrow[r] = -1e30f; lsum[r] = 0.f; }

    const int ntiles = (q0 >> 6) + 1;

    // prologue: stage tile 0 into buffer 0
#pragma unroll
    for (int i = 0; i < 2; ++i) {
        int c = w * 2 + i;
        GLD16(Kg + (size_t)(c * 8 + lrow8) * HD + lchunk * 8, &Ks[0][c * 512]);
        GLD16(Vg + (size_t)(c * 8 + lrow8) * TSEQ + lchunk * 8, &Vs[0][c * 512]);
    }
    __syncthreads();

    int cur = 0;
    for (int kt = 0; kt < ntiles; ++kt) {
        // prefetch next tile into the other buffer (overlaps with compute)
        if (kt + 1 < ntiles) {
            int nb = cur ^ 1;
#pragma unroll
            for (int i = 0; i < 2; ++i) {
                int c = w * 2 + i;
                GLD16(Kg + (size_t)((kt + 1) * 64 + c * 8 + lrow8) * HD + lchunk * 8,
                      &Ks[nb][c * 512]);
                GLD16(Vg + (size_t)(c * 8 + lrow8) * TSEQ + (kt + 1) * 64 + lchunk * 8,
                      &Vs[nb][c * 512]);
            }
        }
        const u16* Kc = Ks[cur];
        const u16* Vc = Vs[cur];

        // S = Q K^T  (16 q-rows per wave x 64 k-cols)
        f32x4 s[4] = {};
#pragma unroll
        for (int f = 0; f < 4; ++f)
#pragma unroll
            for (int ks = 0; ks < 2; ++ks) {
                bf16x8 bk = *reinterpret_cast<const bf16x8*>(
                    Kc + (f * 16 + l15) * 64 + (((ks * 4 + g) ^ (l15 & 7)) * 8));
                s[f] = __builtin_amdgcn_mfma_f32_16x16x32_bf16(qa[ks], bk, s[f], 0, 0, 0);
            }
        const bool diag = (kt == ntiles - 1);
        float p[4][4];
#pragma unroll
        for (int f = 0; f < 4; ++f)
#pragma unroll
            for (int r = 0; r < 4; ++r) {
                float sv = s[f][r] * 0.125f;
                if (diag) {
                    int kg = (kt << 6) + f * 16 + l15;
                    int qg = q0 + w * 16 + g * 4 + r;
                    if (kg > qg) sv = -1e30f;
                }
                p[f][r] = sv;
            }
        // online softmax per q-row (reduce over 16-lane group)
#pragma unroll
        for (int r = 0; r < 4; ++r) {
            float rmax = fmaxf(fmaxf(p[0][r], p[1][r]), fmaxf(p[2][r], p[3][r]));
#pragma unroll
            for (int msk = 8; msk; msk >>= 1)
                rmax = fmaxf(rmax, __shfl_xor(rmax, msk));
            float mnew = fmaxf(mrow[r], rmax);
            float alpha = __expf(mrow[r] - mnew);
            mrow[r] = mnew;
            float rsum = 0.f;
#pragma unroll
            for (int f = 0; f < 4; ++f) {
                float pe = __expf(p[f][r] - mnew);
                p[f][r] = pe;
                rsum += pe;
            }
#pragma unroll
            for (int msk = 8; msk; msk >>= 1)
                rsum += __shfl_xor(rsum, msk);
            lsum[r] = lsum[r] * alpha + rsum;
#pragma unroll
            for (int nf = 0; nf < 4; ++nf)
                o[nf][r] *= alpha;
        }
        // P -> LDS (wave-private, swizzled; no cross-wave barrier needed)
#pragma unroll
        for (int f = 0; f < 4; ++f)
#pragma unroll
            for (int r = 0; r < 4; ++r) {
                int prow = g * 4 + r;
                int col = f * 16 + l15;
                Ps[w][prow * 64 + (((col >> 3) ^ (prow & 7)) * 8) + (col & 7)] = f2bf(p[f][r]);
            }
        // O += P V   (A-frag from Ps, B-frag from swizzled V^T tile)
#pragma unroll
        for (int nf = 0; nf < 4; ++nf)
#pragma unroll
            for (int ks = 0; ks < 2; ++ks) {
                bf16x8 pa = *reinterpret_cast<const bf16x8*>(
                    &Ps[w][l15 * 64 + (((ks * 4 + g) ^ (l15 & 7)) * 8)]);
                bf16x8 bv = *reinterpret_cast<const bf16x8*>(
                    Vc + (nf * 16 + l15) * 64 + (((ks * 4 + g) ^ (l15 & 7)) * 8));
                o[nf] = __builtin_amdgcn_mfma_f32_16x16x32_bf16(pa, bv, o[nf], 0, 0, 0);
            }
        __syncthreads();  // drains vmcnt (prefetch) + protects buffer reuse
        cur ^= 1;
    }
    // epilogue: attn_out[b*T+q][h*64+d] bf16
#pragma unroll
    for (int nf = 0; nf < 4; ++nf)
#pragma unroll
        for (int r = 0; r < 4; ++r) {
            int q = q0 + w * 16 + g * 4 + r;
            int d = nf * 16 + l15;
            float val = o[nf][r] / lsum[r];
            attn_out[(size_t)(b * TSEQ + q) * NE + h * HD + d] = f2bf(val);
        }
}

extern "C" void kernel_launch(void* const* d_in, const int* in_sizes, int n_in,
                              void* d_out, int out_size, void* d_ws, size_t ws_size,
                              hipStream_t stream) {
    const float* x = (const float*)d_in[0];
    const float* W_attn = (const float*)d_in[1];
    const float* b_attn = (const float*)d_in[2];
    const float* W_proj = (const float*)d_in[3];
    const float* b_proj = (const float*)d_in[4];
    float* out = (float*)d_out;

    char* ws = (char*)d_ws;
    u16* xb   = (u16*)(ws);                          // [4096,1024] bf16, 8MB
    u16* WaT  = (u16*)(ws + 8u * 1024 * 1024);       // [3072,1024] bf16, 6MB
    u16* WpT  = (u16*)(ws + 14u * 1024 * 1024);      // [1024,1024] bf16, 2MB
    u16* qkvb = (u16*)(ws + 16u * 1024 * 1024);      // q,k [B,H,T,D], v [B,H,D,T], 24MB
    u16* attn = (u16*)(ws + 40u * 1024 * 1024);      // [4096,1024] bf16, 8MB

    const int M = BATCH * TSEQ;  // 4096

    k_f32_to_bf16<<<2048, 256, 0, stream>>>(x, xb, (M * NE) / 4);
    k_transpose_bf16<<<dim3(3 * NE / 32, NE / 32), dim3(32, 8), 0, stream>>>(W_attn, WaT, NE, 3 * NE);
    k_transpose_bf16<<<dim3(NE / 32, NE / 32), dim3(32, 8), 0, stream>>>(W_proj, WpT, NE, NE);

    k_gemm_bt<0><<<dim3(M / 128, (3 * NE) / 128), 256, 0, stream>>>(xb, WaT, b_attn, qkvb, M, 3 * NE, NE);

    const size_t headsz = (size_t)BATCH * NH * TSEQ * HD;  // 4M elems
    k_attn<<<dim3(TSEQ / 64, BATCH * NH), 256, 0, stream>>>(qkvb, qkvb + headsz, qkvb + 2 * headsz, attn);

    k_gemm_bt<1><<<dim3(M / 128, NE / 128), 256, 0, stream>>>(attn, WpT, b_proj, out, M, NE, NE);
}

// Round 3
// 160.855 us; speedup vs baseline: 1.4697x; 1.1862x over previous
//
#include <hip/hip_runtime.h>
#include <hip/hip_bf16.h>

#define NE 1024       // N_EMBD
#define NH 16         // N_HEAD
#define HD 64         // HEAD_SIZE
#define TSEQ 2048
#define BATCH 2

typedef __attribute__((ext_vector_type(8))) short bf16x8;
typedef __attribute__((ext_vector_type(4))) float f32x4;
typedef unsigned short u16;

__device__ inline u16 f2bf(float f) {
    __hip_bfloat16 h = __float2bfloat16(f);
    return *reinterpret_cast<u16*>(&h);
}

#define GLD16(gptr, lptr)                                                        \
    __builtin_amdgcn_global_load_lds(                                            \
        (const __attribute__((address_space(1))) void*)(gptr),                   \
        (__attribute__((address_space(3))) void*)(lptr), 16, 0, 0)

// ---------- elementwise f32 -> bf16 ----------
__global__ void k_f32_to_bf16(const float* __restrict__ in, u16* __restrict__ out, int n4) {
    int i = blockIdx.x * blockDim.x + threadIdx.x;
    int stride = gridDim.x * blockDim.x;
    for (; i < n4; i += stride) {
        float4 v = reinterpret_cast<const float4*>(in)[i];
        ushort4 o;
        o.x = f2bf(v.x); o.y = f2bf(v.y); o.z = f2bf(v.z); o.w = f2bf(v.w);
        reinterpret_cast<ushort4*>(out)[i] = o;
    }
}

// ---------- transpose + convert: in [K][N] f32 -> out [N][K] bf16 ----------
__global__ void k_transpose_bf16(const float* __restrict__ in, u16* __restrict__ out,
                                 int K, int N) {
    __shared__ float tile[32][33];
    int bn = blockIdx.x * 32;
    int bk = blockIdx.y * 32;
    int tx = threadIdx.x, ty = threadIdx.y;
#pragma unroll
    for (int i = 0; i < 32; i += 8)
        tile[ty + i][tx] = in[(size_t)(bk + ty + i) * N + bn + tx];
    __syncthreads();
#pragma unroll
    for (int i = 0; i < 32; i += 8)
        out[(size_t)(bn + ty + i) * K + bk + tx] = f2bf(tile[tx][ty + i]);
}

// ---------- GEMM: C[M,N] = A[M,K] * Bt[N,K]^T + bias ----------
// MODE 0: scatter q/k -> [B,H,T,D] bf16, v -> [B,H,D,T] bf16 (transposed)
// MODE 1: plain f32 out
template <int MODE>
__global__ __launch_bounds__(256, 2) void k_gemm_bt(
    const u16* __restrict__ A, const u16* __restrict__ Bt,
    const float* __restrict__ bias, void* __restrict__ outp,
    int M, int N, int K) {
    __shared__ __align__(16) u16 As[128 * 32];
    __shared__ __align__(16) u16 Bs[128 * 32];
    const int l = threadIdx.x & 63;
    const int w = threadIdx.x >> 6;
    const int m0 = blockIdx.x * 128;
    const int n0 = blockIdx.y * 128;
    const int wr = w >> 1, wc = w & 1;

    f32x4 acc[4][4] = {};
    const int nkt = K >> 5;
    for (int kt = 0; kt < nkt; ++kt) {
        __syncthreads();
#pragma unroll
        for (int i = 0; i < 2; ++i) {
            int c = w * 2 + i;
            const u16* gA = A + (size_t)(m0 + c * 16 + (l >> 2)) * K + (kt << 5) + (l & 3) * 8;
            const u16* gB = Bt + (size_t)(n0 + c * 16 + (l >> 2)) * K + (kt << 5) + (l & 3) * 8;
            GLD16(gA, As + c * 512);
            GLD16(gB, Bs + c * 512);
        }
        __syncthreads();
        bf16x8 af[4], bfr[4];
#pragma unroll
        for (int mi = 0; mi < 4; ++mi)
            af[mi] = *reinterpret_cast<const bf16x8*>(As + (wr * 64 + mi * 16 + (l & 15)) * 32 + (l >> 4) * 8);
#pragma unroll
        for (int ni = 0; ni < 4; ++ni)
            bfr[ni] = *reinterpret_cast<const bf16x8*>(Bs + (wc * 64 + ni * 16 + (l & 15)) * 32 + (l >> 4) * 8);
#pragma unroll
        for (int mi = 0; mi < 4; ++mi)
#pragma unroll
            for (int ni = 0; ni < 4; ++ni)
                acc[mi][ni] = __builtin_amdgcn_mfma_f32_16x16x32_bf16(af[mi], bfr[ni], acc[mi][ni], 0, 0, 0);
    }

    if (MODE == 1) {
        float* C = (float*)outp;
#pragma unroll
        for (int mi = 0; mi < 4; ++mi)
#pragma unroll
            for (int ni = 0; ni < 4; ++ni) {
                int n = n0 + wc * 64 + ni * 16 + (l & 15);
                float bv = bias[n];
#pragma unroll
                for (int r = 0; r < 4; ++r) {
                    int m = m0 + wr * 64 + mi * 16 + (l >> 4) * 4 + r;
                    C[(size_t)m * N + n] = acc[mi][ni][r] + bv;
                }
            }
    } else {
        u16* qkv = (u16*)outp;
        const size_t headsz = (size_t)BATCH * NH * TSEQ * HD;
#pragma unroll
        for (int mi = 0; mi < 4; ++mi)
#pragma unroll
            for (int ni = 0; ni < 4; ++ni) {
                int n = n0 + wc * 64 + ni * 16 + (l & 15);
                float bv = bias[n];
                int which = n >> 10;
                int c = n & 1023;
                int h = c >> 6, d = c & 63;
#pragma unroll
                for (int r = 0; r < 4; ++r) {
                    int m = m0 + wr * 64 + mi * 16 + (l >> 4) * 4 + r;
                    int b = m >> 11, t = m & 2047;
                    float v = acc[mi][ni][r] + bv;
                    size_t dst;
                    if (which == 2)  // V stored transposed: [B,H,D,T]
                        dst = 2 * headsz + ((size_t)(b * NH + h) * HD + d) * TSEQ + t;
                    else
                        dst = (size_t)which * headsz + ((size_t)(b * NH + h) * TSEQ + t) * HD + d;
                    qkv[dst] = f2bf(v);
                }
            }
    }
}

// ---------- causal flash attention, per-wave causal pairing ----------
// 1D grid of 512 blocks. Block -> (bh, pair j). Block handles q-tiles {j, 31-j}:
// each wave owns 16 rows of the HEAVY tile (31-j) and 16 rows of the LIGHT tile (j).
// Per K-tile kt: heavy fragment always computes; light only while kt <= j.
// => every wave does exactly 33 fragment-tile units; K/V LDS frags shared by both.
__global__ __launch_bounds__(256, 2) void k_attn(
    const u16* __restrict__ qb, const u16* __restrict__ kb, const u16* __restrict__ vtb,
    u16* __restrict__ attn_out) {
    __shared__ __align__(16) u16 Ks[2][64 * 64];
    __shared__ __align__(16) u16 Vs[2][64 * 64];
    __shared__ __align__(16) u16 Ps[4][2][16 * 64];
    const int l = threadIdx.x & 63;
    const int w = threadIdx.x >> 6;
    const int g = l >> 4, l15 = l & 15;

    const int bid = blockIdx.x;
    const int bh = bid >> 4;
    const int j = (bid ^ (bid >> 4)) & 15;  // scramble so same-CU blocks differ in j
    const int hvy = 31 - j;
    const int q0h = hvy * 64;
    const int q0l = j * 64;

    const int b = bh >> 4, h = bh & 15;
    const size_t base = (size_t)bh * TSEQ * HD;
    const u16* Q = qb + base;
    const u16* Kg = kb + base;
    const u16* Vg = vtb + base;  // [64 d][2048 t]

    // staging lane decomposition: 8 rows x 8 chunks of 8 elems per 1KB call
    const int lrow8 = l >> 3;
    const int lchunk = (l & 7) ^ lrow8;  // inverse-swizzled source chunk

    bf16x8 qah[2], qal[2];
    {
        const int qrh = q0h + w * 16 + l15;
        const int qrl = q0l + w * 16 + l15;
        qah[0] = *reinterpret_cast<const bf16x8*>(Q + (size_t)qrh * HD + g * 8);
        qah[1] = *reinterpret_cast<const bf16x8*>(Q + (size_t)qrh * HD + 32 + g * 8);
        qal[0] = *reinterpret_cast<const bf16x8*>(Q + (size_t)qrl * HD + g * 8);
        qal[1] = *reinterpret_cast<const bf16x8*>(Q + (size_t)qrl * HD + 32 + g * 8);
    }

    float mh[4], lh[4], ml[4], ll[4];
    f32x4 oh[4] = {}, ol[4] = {};
#pragma unroll
    for (int r = 0; r < 4; ++r) { mh[r] = -1e30f; lh[r] = 0.f; ml[r] = -1e30f; ll[r] = 0.f; }

    const int ntiles = hvy + 1;  // 32 - j

    // softmax + P-store for one fragment set
    auto process = [&](f32x4* s, float* mr, float* ls, f32x4* o, u16* psb,
                       bool diag, int kt, int q0t) {
        float p[4][4];
#pragma unroll
        for (int f = 0; f < 4; ++f)
#pragma unroll
            for (int r = 0; r < 4; ++r) {
                float sv = s[f][r] * 0.125f;
                if (diag) {
                    int kg = (kt << 6) + f * 16 + l15;
                    int qg = q0t + w * 16 + g * 4 + r;
                    if (kg > qg) sv = -1e30f;
                }
                p[f][r] = sv;
            }
#pragma unroll
        for (int r = 0; r < 4; ++r) {
            float rmax = fmaxf(fmaxf(p[0][r], p[1][r]), fmaxf(p[2][r], p[3][r]));
#pragma unroll
            for (int msk = 8; msk; msk >>= 1)
                rmax = fmaxf(rmax, __shfl_xor(rmax, msk));
            float mnew = fmaxf(mr[r], rmax);
            float alpha = __expf(mr[r] - mnew);
            mr[r] = mnew;
            float rsum = 0.f;
#pragma unroll
            for (int f = 0; f < 4; ++f) {
                float pe = __expf(p[f][r] - mnew);
                p[f][r] = pe;
                rsum += pe;
            }
#pragma unroll
            for (int msk = 8; msk; msk >>= 1)
                rsum += __shfl_xor(rsum, msk);
            ls[r] = ls[r] * alpha + rsum;
#pragma unroll
            for (int nf = 0; nf < 4; ++nf)
                o[nf][r] *= alpha;
        }
#pragma unroll
        for (int f = 0; f < 4; ++f)
#pragma unroll
            for (int r = 0; r < 4; ++r) {
                int prow = g * 4 + r;
                int col = f * 16 + l15;
                psb[prow * 64 + (((col >> 3) ^ (prow & 7)) * 8) + (col & 7)] = f2bf(p[f][r]);
            }
    };

    // prologue: stage tile 0 into buffer 0
#pragma unroll
    for (int i = 0; i < 2; ++i) {
        int c = w * 2 + i;
        GLD16(Kg + (size_t)(c * 8 + lrow8) * HD + lchunk * 8, &Ks[0][c * 512]);
        GLD16(Vg + (size_t)(c * 8 + lrow8) * TSEQ + lchunk * 8, &Vs[0][c * 512]);
    }
    __syncthreads();

    int cur = 0;
    for (int kt = 0; kt < ntiles; ++kt) {
        if (kt + 1 < ntiles) {
            int nb = cur ^ 1;
#pragma unroll
            for (int i = 0; i < 2; ++i) {
                int c = w * 2 + i;
                GLD16(Kg + (size_t)((kt + 1) * 64 + c * 8 + lrow8) * HD + lchunk * 8,
                      &Ks[nb][c * 512]);
                GLD16(Vg + (size_t)(c * 8 + lrow8) * TSEQ + (kt + 1) * 64 + lchunk * 8,
                      &Vs[nb][c * 512]);
            }
        }
        const u16* Kc = Ks[cur];
        const u16* Vc = Vs[cur];
        const bool doLight = (kt <= j);

        // S = Q K^T ; K-fragment shared between heavy and light sets
        f32x4 sh[4] = {}, sl[4] = {};
        __builtin_amdgcn_s_setprio(1);
#pragma unroll
        for (int f = 0; f < 4; ++f)
#pragma unroll
            for (int ks = 0; ks < 2; ++ks) {
                bf16x8 bk = *reinterpret_cast<const bf16x8*>(
                    Kc + (f * 16 + l15) * 64 + (((ks * 4 + g) ^ (l15 & 7)) * 8));
                sh[f] = __builtin_amdgcn_mfma_f32_16x16x32_bf16(qah[ks], bk, sh[f], 0, 0, 0);
                if (doLight)
                    sl[f] = __builtin_amdgcn_mfma_f32_16x16x32_bf16(qal[ks], bk, sl[f], 0, 0, 0);
            }
        __builtin_amdgcn_s_setprio(0);

        process(sh, mh, lh, oh, &Ps[w][0][0], kt == hvy, kt, q0h);
        if (doLight) process(sl, ml, ll, ol, &Ps[w][1][0], kt == j, kt, q0l);

        // O += P V ; V-fragment shared
        __builtin_amdgcn_s_setprio(1);
#pragma unroll
        for (int nf = 0; nf < 4; ++nf)
#pragma unroll
            for (int ks = 0; ks < 2; ++ks) {
                int slot = ((ks * 4 + g) ^ (l15 & 7)) * 8;
                bf16x8 bv = *reinterpret_cast<const bf16x8*>(Vc + (nf * 16 + l15) * 64 + slot);
                bf16x8 pah = *reinterpret_cast<const bf16x8*>(&Ps[w][0][l15 * 64 + slot]);
                oh[nf] = __builtin_amdgcn_mfma_f32_16x16x32_bf16(pah, bv, oh[nf], 0, 0, 0);
                if (doLight) {
                    bf16x8 pal = *reinterpret_cast<const bf16x8*>(&Ps[w][1][l15 * 64 + slot]);
                    ol[nf] = __builtin_amdgcn_mfma_f32_16x16x32_bf16(pal, bv, ol[nf], 0, 0, 0);
                }
            }
        __builtin_amdgcn_s_setprio(0);
        __syncthreads();  // drains vmcnt (prefetch) + protects buffer reuse
        cur ^= 1;
    }

    // epilogue: attn_out[b*T+q][h*64+d] bf16
#pragma unroll
    for (int nf = 0; nf < 4; ++nf)
#pragma unroll
        for (int r = 0; r < 4; ++r) {
            int d = nf * 16 + l15;
            int qh_ = q0h + w * 16 + g * 4 + r;
            attn_out[(size_t)(b * TSEQ + qh_) * NE + h * HD + d] = f2bf(oh[nf][r] / lh[r]);
            int ql_ = q0l + w * 16 + g * 4 + r;
            attn_out[(size_t)(b * TSEQ + ql_) * NE + h * HD + d] = f2bf(ol[nf][r] / ll[r]);
        }
}

extern "C" void kernel_launch(void* const* d_in, const int* in_sizes, int n_in,
                              void* d_out, int out_size, void* d_ws, size_t ws_size,
                              hipStream_t stream) {
    const float* x = (const float*)d_in[0];
    const float* W_attn = (const float*)d_in[1];
    const float* b_attn = (const float*)d_in[2];
    const float* W_proj = (const float*)d_in[3];
    const float* b_proj = (const float*)d_in[4];
    float* out = (float*)d_out;

    char* ws = (char*)d_ws;
    u16* xb   = (u16*)(ws);                          // [4096,1024] bf16, 8MB
    u16* WaT  = (u16*)(ws + 8u * 1024 * 1024);       // [3072,1024] bf16, 6MB
    u16* WpT  = (u16*)(ws + 14u * 1024 * 1024);      // [1024,1024] bf16, 2MB
    u16* qkvb = (u16*)(ws + 16u * 1024 * 1024);      // q,k [B,H,T,D], v [B,H,D,T], 24MB
    u16* attn = (u16*)(ws + 40u * 1024 * 1024);      // [4096,1024] bf16, 8MB

    const int M = BATCH * TSEQ;  // 4096

    k_f32_to_bf16<<<2048, 256, 0, stream>>>(x, xb, (M * NE) / 4);
    k_transpose_bf16<<<dim3(3 * NE / 32, NE / 32), dim3(32, 8), 0, stream>>>(W_attn, WaT, NE, 3 * NE);
    k_transpose_bf16<<<dim3(NE / 32, NE / 32), dim3(32, 8), 0, stream>>>(W_proj, WpT, NE, NE);

    k_gemm_bt<0><<<dim3(M / 128, (3 * NE) / 128), 256, 0, stream>>>(xb, WaT, b_attn, qkvb, M, 3 * NE, NE);

    const size_t headsz = (size_t)BATCH * NH * TSEQ * HD;  // 4M elems
    k_attn<<<dim3((TSEQ / 128) * BATCH * NH), 256, 0, stream>>>(qkvb, qkvb + headsz, qkvb + 2 * headsz, attn);

    k_gemm_bt<1><<<dim3(M / 128, NE / 128), 256, 0, stream>>>(attn, WpT, b_proj, out, M, NE, NE);
}

// Round 4
// 153.179 us; speedup vs baseline: 1.5433x; 1.0501x over previous
//
#include <hip/hip_runtime.h>
#include <hip/hip_bf16.h>

#define NE 1024       // N_EMBD
#define NH 16         // N_HEAD
#define HD 64         // HEAD_SIZE
#define TSEQ 2048
#define BATCH 2

typedef __attribute__((ext_vector_type(8))) short bf16x8;
typedef __attribute__((ext_vector_type(4))) float f32x4;
typedef unsigned short u16;

__device__ inline u16 f2bf(float f) {
    __hip_bfloat16 h = __float2bfloat16(f);
    return *reinterpret_cast<u16*>(&h);
}

#define GLD16(gptr, lptr)                                                        \
    __builtin_amdgcn_global_load_lds(                                            \
        (const __attribute__((address_space(1))) void*)(gptr),                   \
        (__attribute__((address_space(3))) void*)(lptr), 16, 0, 0)

// ---------- elementwise f32 -> bf16 ----------
__global__ void k_f32_to_bf16(const float* __restrict__ in, u16* __restrict__ out, int n4) {
    int i = blockIdx.x * blockDim.x + threadIdx.x;
    int stride = gridDim.x * blockDim.x;
    for (; i < n4; i += stride) {
        float4 v = reinterpret_cast<const float4*>(in)[i];
        ushort4 o;
        o.x = f2bf(v.x); o.y = f2bf(v.y); o.z = f2bf(v.z); o.w = f2bf(v.w);
        reinterpret_cast<ushort4*>(out)[i] = o;
    }
}

// ---------- transpose + convert: in [K][N] f32 -> out [N][K] bf16 ----------
__global__ void k_transpose_bf16(const float* __restrict__ in, u16* __restrict__ out,
                                 int K, int N) {
    __shared__ float tile[32][33];
    int bn = blockIdx.x * 32;
    int bk = blockIdx.y * 32;
    int tx = threadIdx.x, ty = threadIdx.y;
#pragma unroll
    for (int i = 0; i < 32; i += 8)
        tile[ty + i][tx] = in[(size_t)(bk + ty + i) * N + bn + tx];
    __syncthreads();
#pragma unroll
    for (int i = 0; i < 32; i += 8)
        out[(size_t)(bn + ty + i) * K + bk + tx] = f2bf(tile[tx][ty + i]);
}

// ---------- GEMM: C[M,N] = A[M,K] * Bt[N,K]^T + bias ----------
// MODE 0: scatter q/k -> [B,H,T,D] bf16, v -> [B,H,D,T] bf16 (transposed)
// MODE 1: plain f32 out
template <int MODE>
__global__ __launch_bounds__(256, 2) void k_gemm_bt(
    const u16* __restrict__ A, const u16* __restrict__ Bt,
    const float* __restrict__ bias, void* __restrict__ outp,
    int M, int N, int K) {
    __shared__ __align__(16) u16 As[128 * 32];
    __shared__ __align__(16) u16 Bs[128 * 32];
    const int l = threadIdx.x & 63;
    const int w = threadIdx.x >> 6;
    const int m0 = blockIdx.x * 128;
    const int n0 = blockIdx.y * 128;
    const int wr = w >> 1, wc = w & 1;

    f32x4 acc[4][4] = {};
    const int nkt = K >> 5;
    for (int kt = 0; kt < nkt; ++kt) {
        __syncthreads();
#pragma unroll
        for (int i = 0; i < 2; ++i) {
            int c = w * 2 + i;
            const u16* gA = A + (size_t)(m0 + c * 16 + (l >> 2)) * K + (kt << 5) + (l & 3) * 8;
            const u16* gB = Bt + (size_t)(n0 + c * 16 + (l >> 2)) * K + (kt << 5) + (l & 3) * 8;
            GLD16(gA, As + c * 512);
            GLD16(gB, Bs + c * 512);
        }
        __syncthreads();
        bf16x8 af[4], bfr[4];
#pragma unroll
        for (int mi = 0; mi < 4; ++mi)
            af[mi] = *reinterpret_cast<const bf16x8*>(As + (wr * 64 + mi * 16 + (l & 15)) * 32 + (l >> 4) * 8);
#pragma unroll
        for (int ni = 0; ni < 4; ++ni)
            bfr[ni] = *reinterpret_cast<const bf16x8*>(Bs + (wc * 64 + ni * 16 + (l & 15)) * 32 + (l >> 4) * 8);
#pragma unroll
        for (int mi = 0; mi < 4; ++mi)
#pragma unroll
            for (int ni = 0; ni < 4; ++ni)
                acc[mi][ni] = __builtin_amdgcn_mfma_f32_16x16x32_bf16(af[mi], bfr[ni], acc[mi][ni], 0, 0, 0);
    }

    if (MODE == 1) {
        float* C = (float*)outp;
#pragma unroll
        for (int mi = 0; mi < 4; ++mi)
#pragma unroll
            for (int ni = 0; ni < 4; ++ni) {
                int n = n0 + wc * 64 + ni * 16 + (l & 15);
                float bv = bias[n];
#pragma unroll
                for (int r = 0; r < 4; ++r) {
                    int m = m0 + wr * 64 + mi * 16 + (l >> 4) * 4 + r;
                    C[(size_t)m * N + n] = acc[mi][ni][r] + bv;
                }
            }
    } else {
        u16* qkv = (u16*)outp;
        const size_t headsz = (size_t)BATCH * NH * TSEQ * HD;
#pragma unroll
        for (int mi = 0; mi < 4; ++mi)
#pragma unroll
            for (int ni = 0; ni < 4; ++ni) {
                int n = n0 + wc * 64 + ni * 16 + (l & 15);
                float bv = bias[n];
                int which = n >> 10;
                int c = n & 1023;
                int h = c >> 6, d = c & 63;
#pragma unroll
                for (int r = 0; r < 4; ++r) {
                    int m = m0 + wr * 64 + mi * 16 + (l >> 4) * 4 + r;
                    int b = m >> 11, t = m & 2047;
                    float v = acc[mi][ni][r] + bv;
                    size_t dst;
                    if (which == 2)  // V stored transposed: [B,H,D,T]
                        dst = 2 * headsz + ((size_t)(b * NH + h) * HD + d) * TSEQ + t;
                    else
                        dst = (size_t)which * headsz + ((size_t)(b * NH + h) * TSEQ + t) * HD + d;
                    qkv[dst] = f2bf(v);
                }
            }
    }
}

// ---------- causal flash attention ----------
// grid: 1024 blocks (32 q-tiles x 32 bh), 4 waves, 40KB LDS -> 4 blocks/CU,
// all blocks co-resident (16 waves/CU). Per-CU work is equalized analytically:
// co-resident blocks differ by 256 in bid -> i differs by 8; j = hi*8 + zig(lo)
// makes each CU's four (j+1) tile-counts sum to exactly 66.
__global__ __launch_bounds__(256, 4) void k_attn(
    const u16* __restrict__ qb, const u16* __restrict__ kb, const u16* __restrict__ vtb,
    u16* __restrict__ attn_out) {
    __shared__ __align__(16) u16 Ks[2][64 * 64];
    __shared__ __align__(16) u16 Vs[2][64 * 64];
    __shared__ __align__(16) u16 Ps[4][16 * 64];
    const int l = threadIdx.x & 63;
    const int w = threadIdx.x >> 6;
    const int g = l >> 4, l15 = l & 15;

    const int bid = blockIdx.x;
    const int i = bid >> 5;           // 0..31
    const int bh = bid & 31;
    const int hi = i >> 3, lo = i & 7;
    const int j = hi * 8 + ((hi & 1) ? (7 - lo) : lo);  // q-tile index, CU-balanced
    const int q0 = j * 64;

    const int b = bh >> 4, h = bh & 15;
    const size_t base = (size_t)bh * TSEQ * HD;
    const u16* Q = qb + base;
    const u16* Kg = kb + base;
    const u16* Vg = vtb + base;  // [64 d][2048 t]

    // staging lane decomposition: 8 rows x 8 chunks of 8 elems per 1KB call
    const int lrow8 = l >> 3;
    const int lchunk = (l & 7) ^ lrow8;  // inverse-swizzled source chunk

    const int qrow = q0 + w * 16 + l15;
    bf16x8 qa[2];
    qa[0] = *reinterpret_cast<const bf16x8*>(Q + (size_t)qrow * HD + g * 8);
    qa[1] = *reinterpret_cast<const bf16x8*>(Q + (size_t)qrow * HD + 32 + g * 8);

    float mrow[4], lsum[4];
    f32x4 o[4] = {};
#pragma unroll
    for (int r = 0; r < 4; ++r) { mrow[r] = -1e30f; lsum[r] = 0.f; }

    const int ntiles = j + 1;
    const float SC = 0.125f * 1.44269504f;  // log2(e)/sqrt(64)

    // prologue: stage tile 0 into buffer 0
#pragma unroll
    for (int i2 = 0; i2 < 2; ++i2) {
        int c = w * 2 + i2;
        GLD16(Kg + (size_t)(c * 8 + lrow8) * HD + lchunk * 8, &Ks[0][c * 512]);
        GLD16(Vg + (size_t)(c * 8 + lrow8) * TSEQ + lchunk * 8, &Vs[0][c * 512]);
    }
    __syncthreads();

    int cur = 0;
    for (int kt = 0; kt < ntiles; ++kt) {
        if (kt + 1 < ntiles) {
            int nb = cur ^ 1;
#pragma unroll
            for (int i2 = 0; i2 < 2; ++i2) {
                int c = w * 2 + i2;
                GLD16(Kg + (size_t)((kt + 1) * 64 + c * 8 + lrow8) * HD + lchunk * 8,
                      &Ks[nb][c * 512]);
                GLD16(Vg + (size_t)(c * 8 + lrow8) * TSEQ + (kt + 1) * 64 + lchunk * 8,
                      &Vs[nb][c * 512]);
            }
        }
        const u16* Kc = Ks[cur];
        const u16* Vc = Vs[cur];

        // S = Q K^T (unscaled)
        f32x4 s[4] = {};
        __builtin_amdgcn_s_setprio(1);
#pragma unroll
        for (int f = 0; f < 4; ++f)
#pragma unroll
            for (int ks = 0; ks < 2; ++ks) {
                bf16x8 bk = *reinterpret_cast<const bf16x8*>(
                    Kc + (f * 16 + l15) * 64 + (((ks * 4 + g) ^ (l15 & 7)) * 8));
                s[f] = __builtin_amdgcn_mfma_f32_16x16x32_bf16(qa[ks], bk, s[f], 0, 0, 0);
            }
        __builtin_amdgcn_s_setprio(0);

        const bool diag = (kt == ntiles - 1);
        if (diag) {
#pragma unroll
            for (int f = 0; f < 4; ++f)
#pragma unroll
                for (int r = 0; r < 4; ++r) {
                    int kg = (kt << 6) + f * 16 + l15;
                    int qg = q0 + w * 16 + g * 4 + r;
                    if (kg > qg) s[f][r] = -1e30f;
                }
        }
        // online softmax per q-row, unscaled domain; exp via exp2(fma)
        float p[4][4];
#pragma unroll
        for (int r = 0; r < 4; ++r) {
            float rmax = fmaxf(fmaxf(s[0][r], s[1][r]), fmaxf(s[2][r], s[3][r]));
#pragma unroll
            for (int msk = 8; msk; msk >>= 1)
                rmax = fmaxf(rmax, __shfl_xor(rmax, msk));
            float mnew = fmaxf(mrow[r], rmax);
            float alpha = exp2f((mrow[r] - mnew) * SC);
            mrow[r] = mnew;
            float mc = mnew * SC;
            float rsum = 0.f;
#pragma unroll
            for (int f = 0; f < 4; ++f) {
                float pe = exp2f(__builtin_fmaf(s[f][r], SC, -mc));
                p[f][r] = pe;
                rsum += pe;
            }
#pragma unroll
            for (int msk = 8; msk; msk >>= 1)
                rsum += __shfl_xor(rsum, msk);
            lsum[r] = lsum[r] * alpha + rsum;
#pragma unroll
            for (int nf = 0; nf < 4; ++nf)
                o[nf][r] *= alpha;
        }
        // P -> LDS (wave-private, swizzled)
#pragma unroll
        for (int f = 0; f < 4; ++f)
#pragma unroll
            for (int r = 0; r < 4; ++r) {
                int prow = g * 4 + r;
                int col = f * 16 + l15;
                Ps[w][prow * 64 + (((col >> 3) ^ (prow & 7)) * 8) + (col & 7)] = f2bf(p[f][r]);
            }
        // O += P V
        __builtin_amdgcn_s_setprio(1);
#pragma unroll
        for (int nf = 0; nf < 4; ++nf)
#pragma unroll
            for (int ks = 0; ks < 2; ++ks) {
                int slot = ((ks * 4 + g) ^ (l15 & 7)) * 8;
                bf16x8 pa = *reinterpret_cast<const bf16x8*>(&Ps[w][l15 * 64 + slot]);
                bf16x8 bv = *reinterpret_cast<const bf16x8*>(Vc + (nf * 16 + l15) * 64 + slot);
                o[nf] = __builtin_amdgcn_mfma_f32_16x16x32_bf16(pa, bv, o[nf], 0, 0, 0);
            }
        __builtin_amdgcn_s_setprio(0);
        __syncthreads();  // drains vmcnt (prefetch) + protects buffer reuse
        cur ^= 1;
    }

    // epilogue: attn_out[b*T+q][h*64+d] bf16
#pragma unroll
    for (int nf = 0; nf < 4; ++nf)
#pragma unroll
        for (int r = 0; r < 4; ++r) {
            int q = q0 + w * 16 + g * 4 + r;
            int d = nf * 16 + l15;
            attn_out[(size_t)(b * TSEQ + q) * NE + h * HD + d] = f2bf(o[nf][r] / lsum[r]);
        }
}

extern "C" void kernel_launch(void* const* d_in, const int* in_sizes, int n_in,
                              void* d_out, int out_size, void* d_ws, size_t ws_size,
                              hipStream_t stream) {
    const float* x = (const float*)d_in[0];
    const float* W_attn = (const float*)d_in[1];
    const float* b_attn = (const float*)d_in[2];
    const float* W_proj = (const float*)d_in[3];
    const float* b_proj = (const float*)d_in[4];
    float* out = (float*)d_out;

    char* ws = (char*)d_ws;
    u16* xb   = (u16*)(ws);                          // [4096,1024] bf16, 8MB
    u16* WaT  = (u16*)(ws + 8u * 1024 * 1024);       // [3072,1024] bf16, 6MB
    u16* WpT  = (u16*)(ws + 14u * 1024 * 1024);      // [1024,1024] bf16, 2MB
    u16* qkvb = (u16*)(ws + 16u * 1024 * 1024);      // q,k [B,H,T,D], v [B,H,D,T], 24MB
    u16* attn = (u16*)(ws + 40u * 1024 * 1024);      // [4096,1024] bf16, 8MB

    const int M = BATCH * TSEQ;  // 4096

    k_f32_to_bf16<<<2048, 256, 0, stream>>>(x, xb, (M * NE) / 4);
    k_transpose_bf16<<<dim3(3 * NE / 32, NE / 32), dim3(32, 8), 0, stream>>>(W_attn, WaT, NE, 3 * NE);
    k_transpose_bf16<<<dim3(NE / 32, NE / 32), dim3(32, 8), 0, stream>>>(W_proj, WpT, NE, NE);

    k_gemm_bt<0><<<dim3(M / 128, (3 * NE) / 128), 256, 0, stream>>>(xb, WaT, b_attn, qkvb, M, 3 * NE, NE);

    const size_t headsz = (size_t)BATCH * NH * TSEQ * HD;  // 4M elems
    k_attn<<<dim3(32 * BATCH * NH), 256, 0, stream>>>(qkvb, qkvb + headsz, qkvb + 2 * headsz, attn);

    k_gemm_bt<1><<<dim3(M / 128, NE / 128), 256, 0, stream>>>(attn, WpT, b_proj, out, M, NE, NE);
}

// Round 5
// 134.361 us; speedup vs baseline: 1.7595x; 1.1401x over previous
//
#include <hip/hip_runtime.h>
#include <hip/hip_bf16.h>

#define NE 1024       // N_EMBD
#define NH 16         // N_HEAD
#define HD 64         // HEAD_SIZE
#define TSEQ 2048
#define BATCH 2

typedef __attribute__((ext_vector_type(8))) short bf16x8;
typedef __attribute__((ext_vector_type(4))) float f32x4;
typedef __attribute__((ext_vector_type(4))) unsigned int u32x4;
typedef unsigned short u16;
typedef unsigned int u32;

__device__ inline u16 f2bf(float f) {
    __hip_bfloat16 h = __float2bfloat16(f);
    return *reinterpret_cast<u16*>(&h);
}

__device__ inline u32 cvt_pk_bf16(float lo, float hi) {
    u32 r;
    asm("v_cvt_pk_bf16_f32 %0, %1, %2" : "=v"(r) : "v"(lo), "v"(hi));
    return r;
}

#define GLD16(gptr, lptr)                                                        \
    __builtin_amdgcn_global_load_lds(                                            \
        (const __attribute__((address_space(1))) void*)(gptr),                   \
        (__attribute__((address_space(3))) void*)(lptr), 16, 0, 0)

// ---------- elementwise f32 -> bf16 ----------
__global__ void k_f32_to_bf16(const float* __restrict__ in, u16* __restrict__ out, int n4) {
    int i = blockIdx.x * blockDim.x + threadIdx.x;
    int stride = gridDim.x * blockDim.x;
    for (; i < n4; i += stride) {
        float4 v = reinterpret_cast<const float4*>(in)[i];
        ushort4 o;
        o.x = f2bf(v.x); o.y = f2bf(v.y); o.z = f2bf(v.z); o.w = f2bf(v.w);
        reinterpret_cast<ushort4*>(out)[i] = o;
    }
}

// ---------- transpose + convert: in [K][N] f32 -> out [N][K] bf16 ----------
__global__ void k_transpose_bf16(const float* __restrict__ in, u16* __restrict__ out,
                                 int K, int N) {
    __shared__ float tile[32][33];
    int bn = blockIdx.x * 32;
    int bk = blockIdx.y * 32;
    int tx = threadIdx.x, ty = threadIdx.y;
#pragma unroll
    for (int i = 0; i < 32; i += 8)
        tile[ty + i][tx] = in[(size_t)(bk + ty + i) * N + bn + tx];
    __syncthreads();
#pragma unroll
    for (int i = 0; i < 32; i += 8)
        out[(size_t)(bn + ty + i) * K + bk + tx] = f2bf(tile[tx][ty + i]);
}

// ---------- GEMM: C[M,N] = A[M,K] * Bt[N,K]^T + bias ----------
// MODE 0: scatter q/k -> [B,H,T,D] bf16, v -> [B,H,D,T] bf16 (transposed)
// MODE 1: plain f32 out
template <int MODE>
__global__ __launch_bounds__(256, 2) void k_gemm_bt(
    const u16* __restrict__ A, const u16* __restrict__ Bt,
    const float* __restrict__ bias, void* __restrict__ outp,
    int M, int N, int K) {
    __shared__ __align__(16) u16 As[128 * 32];
    __shared__ __align__(16) u16 Bs[128 * 32];
    const int l = threadIdx.x & 63;
    const int w = threadIdx.x >> 6;
    const int m0 = blockIdx.x * 128;
    const int n0 = blockIdx.y * 128;
    const int wr = w >> 1, wc = w & 1;

    f32x4 acc[4][4] = {};
    const int nkt = K >> 5;
    for (int kt = 0; kt < nkt; ++kt) {
        __syncthreads();
#pragma unroll
        for (int i = 0; i < 2; ++i) {
            int c = w * 2 + i;
            const u16* gA = A + (size_t)(m0 + c * 16 + (l >> 2)) * K + (kt << 5) + (l & 3) * 8;
            const u16* gB = Bt + (size_t)(n0 + c * 16 + (l >> 2)) * K + (kt << 5) + (l & 3) * 8;
            GLD16(gA, As + c * 512);
            GLD16(gB, Bs + c * 512);
        }
        __syncthreads();
        bf16x8 af[4], bfr[4];
#pragma unroll
        for (int mi = 0; mi < 4; ++mi)
            af[mi] = *reinterpret_cast<const bf16x8*>(As + (wr * 64 + mi * 16 + (l & 15)) * 32 + (l >> 4) * 8);
#pragma unroll
        for (int ni = 0; ni < 4; ++ni)
            bfr[ni] = *reinterpret_cast<const bf16x8*>(Bs + (wc * 64 + ni * 16 + (l & 15)) * 32 + (l >> 4) * 8);
#pragma unroll
        for (int mi = 0; mi < 4; ++mi)
#pragma unroll
            for (int ni = 0; ni < 4; ++ni)
                acc[mi][ni] = __builtin_amdgcn_mfma_f32_16x16x32_bf16(af[mi], bfr[ni], acc[mi][ni], 0, 0, 0);
    }

    if (MODE == 1) {
        float* C = (float*)outp;
#pragma unroll
        for (int mi = 0; mi < 4; ++mi)
#pragma unroll
            for (int ni = 0; ni < 4; ++ni) {
                int n = n0 + wc * 64 + ni * 16 + (l & 15);
                float bv = bias[n];
#pragma unroll
                for (int r = 0; r < 4; ++r) {
                    int m = m0 + wr * 64 + mi * 16 + (l >> 4) * 4 + r;
                    C[(size_t)m * N + n] = acc[mi][ni][r] + bv;
                }
            }
    } else {
        u16* qkv = (u16*)outp;
        const size_t headsz = (size_t)BATCH * NH * TSEQ * HD;
#pragma unroll
        for (int mi = 0; mi < 4; ++mi)
#pragma unroll
            for (int ni = 0; ni < 4; ++ni) {
                int n = n0 + wc * 64 + ni * 16 + (l & 15);
                float bv = bias[n];
                int which = n >> 10;
                int c = n & 1023;
                int h = c >> 6, d = c & 63;
#pragma unroll
                for (int r = 0; r < 4; ++r) {
                    int m = m0 + wr * 64 + mi * 16 + (l >> 4) * 4 + r;
                    int b = m >> 11, t = m & 2047;
                    float v = acc[mi][ni][r] + bv;
                    size_t dst;
                    if (which == 2)  // V stored transposed: [B,H,D,T]
                        dst = 2 * headsz + ((size_t)(b * NH + h) * HD + d) * TSEQ + t;
                    else
                        dst = (size_t)which * headsz + ((size_t)(b * NH + h) * TSEQ + t) * HD + d;
                    qkv[dst] = f2bf(v);
                }
            }
    }
}

// ---------- causal flash attention, swapped-QK^T, P-in-registers ----------
// grid: 1024 blocks (32 q-tiles x 32 bh), 4 waves, 32KB LDS.
// S^T = mfma(K-frag, Q-frag): lane (g,l15) holds S^T[k=f*16+g*4+r][q=l15]
// -> softmax is lane-local over 16 regs + 2 shfl_xor across g.
// P packed to bf16 in-reg (cvt_pk) and redistributed via shfl to the PV
// B-frag; O^T = mfma(V^T-frag, P-frag): lane holds O[q=l15][d=nf*16+g*4+r].
__global__ __launch_bounds__(256, 4) void k_attn(
    const u16* __restrict__ qb, const u16* __restrict__ kb, const u16* __restrict__ vtb,
    u16* __restrict__ attn_out) {
    __shared__ __align__(16) u16 Ks[2][64 * 64];
    __shared__ __align__(16) u16 Vs[2][64 * 64];
    const int l = threadIdx.x & 63;
    const int w = threadIdx.x >> 6;
    const int g = l >> 4, l15 = l & 15;

    const int bid = blockIdx.x;
    const int i = bid >> 5;           // 0..31
    const int bh = bid & 31;
    const int hi = i >> 3, lo = i & 7;
    const int j = hi * 8 + ((hi & 1) ? (7 - lo) : lo);  // q-tile index, CU-balanced
    const int q0 = j * 64;

    const int b = bh >> 4, h = bh & 15;
    const size_t base = (size_t)bh * TSEQ * HD;
    const u16* Q = qb + base;
    const u16* Kg = kb + base;
    const u16* Vg = vtb + base;  // [64 d][2048 t]

    // staging lane decomposition: 8 rows x 8 chunks of 8 elems per 1KB call
    const int lrow8 = l >> 3;
    const int lchunk = (l & 7) ^ lrow8;  // inverse-swizzled source chunk

    const int qrow = q0 + w * 16 + l15;  // this lane's q-row (n-dim of S^T)
    bf16x8 qa[2];
    qa[0] = *reinterpret_cast<const bf16x8*>(Q + (size_t)qrow * HD + g * 8);
    qa[1] = *reinterpret_cast<const bf16x8*>(Q + (size_t)qrow * HD + 32 + g * 8);

    float mrow = -1e30f, lsum = 0.f;
    f32x4 o[4] = {};

    const int ntiles = j + 1;
    const float SC = 0.125f * 1.44269504f;  // log2(e)/sqrt(64)
    const float THRU = 8.0f / SC;           // defer-max threshold (unscaled)

    const int srcA = ((2 * g) & 3) * 16 + l15;
    const int srcB = ((2 * g + 1) & 3) * 16 + l15;
    const bool losel = (g < 2);

    // prologue: stage tile 0 into buffer 0
#pragma unroll
    for (int i2 = 0; i2 < 2; ++i2) {
        int c = w * 2 + i2;
        GLD16(Kg + (size_t)(c * 8 + lrow8) * HD + lchunk * 8, &Ks[0][c * 512]);
        GLD16(Vg + (size_t)(c * 8 + lrow8) * TSEQ + lchunk * 8, &Vs[0][c * 512]);
    }
    __syncthreads();

    int cur = 0;
    for (int kt = 0; kt < ntiles; ++kt) {
        if (kt + 1 < ntiles) {
            int nb = cur ^ 1;
#pragma unroll
            for (int i2 = 0; i2 < 2; ++i2) {
                int c = w * 2 + i2;
                GLD16(Kg + (size_t)((kt + 1) * 64 + c * 8 + lrow8) * HD + lchunk * 8,
                      &Ks[nb][c * 512]);
                GLD16(Vg + (size_t)(c * 8 + lrow8) * TSEQ + (kt + 1) * 64 + lchunk * 8,
                      &Vs[nb][c * 512]);
            }
        }
        const u16* Kc = Ks[cur];
        const u16* Vc = Vs[cur];

        // S^T = mfma(A=K-frag, B=Q-frag): s[f][r] = S[q=qrow][k=kt*64+f*16+g*4+r]
        f32x4 s[4] = {};
        __builtin_amdgcn_s_setprio(1);
#pragma unroll
        for (int f = 0; f < 4; ++f)
#pragma unroll
            for (int ks = 0; ks < 2; ++ks) {
                bf16x8 bk = *reinterpret_cast<const bf16x8*>(
                    Kc + (f * 16 + l15) * 64 + (((ks * 4 + g) ^ (l15 & 7)) * 8));
                s[f] = __builtin_amdgcn_mfma_f32_16x16x32_bf16(bk, qa[ks], s[f], 0, 0, 0);
            }
        __builtin_amdgcn_s_setprio(0);

        // causal mask on diagonal tile
        if (kt == ntiles - 1) {
#pragma unroll
            for (int f = 0; f < 4; ++f)
#pragma unroll
                for (int r = 0; r < 4; ++r) {
                    int kg = (kt << 6) + f * 16 + g * 4 + r;
                    if (kg > qrow) s[f][r] = -1e30f;
                }
        }

        // lane-local softmax for row q=qrow (16 vals in-lane + 2 shfl across g)
        float rmax = -1e30f;
#pragma unroll
        for (int f = 0; f < 4; ++f)
            rmax = fmaxf(rmax, fmaxf(fmaxf(s[f][0], s[f][1]), fmaxf(s[f][2], s[f][3])));
        rmax = fmaxf(rmax, __shfl_xor(rmax, 16));
        rmax = fmaxf(rmax, __shfl_xor(rmax, 32));

        if (__any(rmax - mrow > THRU)) {
            float mnew = fmaxf(mrow, rmax);
            float alpha = exp2f((mrow - mnew) * SC);
            mrow = mnew;
            lsum *= alpha;
#pragma unroll
            for (int nf = 0; nf < 4; ++nf)
#pragma unroll
                for (int r = 0; r < 4; ++r)
                    o[nf][r] *= alpha;
        }
        const float mc = mrow * SC;

        float pe[4][4];
        float rsum = 0.f;
#pragma unroll
        for (int f = 0; f < 4; ++f)
#pragma unroll
            for (int r = 0; r < 4; ++r) {
                float v = exp2f(__builtin_fmaf(s[f][r], SC, -mc));
                pe[f][r] = v;
                rsum += v;
            }
        rsum += __shfl_xor(rsum, 16);
        rsum += __shfl_xor(rsum, 32);
        lsum += rsum;

        // pack P to bf16: w0[f] = {k=f*16+g*4, +1}, w1[f] = {+2, +3}
        u32 w0[4], w1[4];
#pragma unroll
        for (int f = 0; f < 4; ++f) {
            w0[f] = cvt_pk_bf16(pe[f][0], pe[f][1]);
            w1[f] = cvt_pk_bf16(pe[f][2], pe[f][3]);
        }

        // O^T += mfma(A=V^T-frag, B=P-frag)
        __builtin_amdgcn_s_setprio(1);
#pragma unroll
        for (int ks = 0; ks < 2; ++ks) {
            // assemble B-frag: lane (g,l15) needs P[q=l15][k=32ks+g*8 .. +7]
            u32 t00 = (u32)__shfl((int)w0[2 * ks], srcA);
            u32 t01 = (u32)__shfl((int)w0[2 * ks + 1], srcA);
            u32 t10 = (u32)__shfl((int)w1[2 * ks], srcA);
            u32 t11 = (u32)__shfl((int)w1[2 * ks + 1], srcA);
            u32 t20 = (u32)__shfl((int)w0[2 * ks], srcB);
            u32 t21 = (u32)__shfl((int)w0[2 * ks + 1], srcB);
            u32 t30 = (u32)__shfl((int)w1[2 * ks], srcB);
            u32 t31 = (u32)__shfl((int)w1[2 * ks + 1], srcB);
            u32x4 bb;
            bb.x = losel ? t00 : t01;
            bb.y = losel ? t10 : t11;
            bb.z = losel ? t20 : t21;
            bb.w = losel ? t30 : t31;
            bf16x8 pb = __builtin_bit_cast(bf16x8, bb);
#pragma unroll
            for (int nf = 0; nf < 4; ++nf) {
                bf16x8 bv = *reinterpret_cast<const bf16x8*>(
                    Vc + (nf * 16 + l15) * 64 + (((ks * 4 + g) ^ (l15 & 7)) * 8));
                o[nf] = __builtin_amdgcn_mfma_f32_16x16x32_bf16(bv, pb, o[nf], 0, 0, 0);
            }
        }
        __builtin_amdgcn_s_setprio(0);
        __syncthreads();  // drains vmcnt (prefetch) + protects buffer reuse
        cur ^= 1;
    }

    // epilogue: lane holds O[q=qrow][d=nf*16+g*4+r]; packed u32 stores
    const float inv = 1.0f / lsum;
    u16* orow = attn_out + (size_t)(b * TSEQ + qrow) * NE + h * HD;
#pragma unroll
    for (int nf = 0; nf < 4; ++nf) {
        int d0 = nf * 16 + g * 4;
        u32 p01 = cvt_pk_bf16(o[nf][0] * inv, o[nf][1] * inv);
        u32 p23 = cvt_pk_bf16(o[nf][2] * inv, o[nf][3] * inv);
        *reinterpret_cast<u32*>(orow + d0) = p01;
        *reinterpret_cast<u32*>(orow + d0 + 2) = p23;
    }
}

extern "C" void kernel_launch(void* const* d_in, const int* in_sizes, int n_in,
                              void* d_out, int out_size, void* d_ws, size_t ws_size,
                              hipStream_t stream) {
    const float* x = (const float*)d_in[0];
    const float* W_attn = (const float*)d_in[1];
    const float* b_attn = (const float*)d_in[2];
    const float* W_proj = (const float*)d_in[3];
    const float* b_proj = (const float*)d_in[4];
    float* out = (float*)d_out;

    char* ws = (char*)d_ws;
    u16* xb   = (u16*)(ws);                          // [4096,1024] bf16, 8MB
    u16* WaT  = (u16*)(ws + 8u * 1024 * 1024);       // [3072,1024] bf16, 6MB
    u16* WpT  = (u16*)(ws + 14u * 1024 * 1024);      // [1024,1024] bf16, 2MB
    u16* qkvb = (u16*)(ws + 16u * 1024 * 1024);      // q,k [B,H,T,D], v [B,H,D,T], 24MB
    u16* attn = (u16*)(ws + 40u * 1024 * 1024);      // [4096,1024] bf16, 8MB

    const int M = BATCH * TSEQ;  // 4096

    k_f32_to_bf16<<<2048, 256, 0, stream>>>(x, xb, (M * NE) / 4);
    k_transpose_bf16<<<dim3(3 * NE / 32, NE / 32), dim3(32, 8), 0, stream>>>(W_attn, WaT, NE, 3 * NE);
    k_transpose_bf16<<<dim3(NE / 32, NE / 32), dim3(32, 8), 0, stream>>>(W_proj, WpT, NE, NE);

    k_gemm_bt<0><<<dim3(M / 128, (3 * NE) / 128), 256, 0, stream>>>(xb, WaT, b_attn, qkvb, M, 3 * NE, NE);

    const size_t headsz = (size_t)BATCH * NH * TSEQ * HD;  // 4M elems
    k_attn<<<dim3(32 * BATCH * NH), 256, 0, stream>>>(qkvb, qkvb + headsz, qkvb + 2 * headsz, attn);

    k_gemm_bt<1><<<dim3(M / 128, NE / 128), 256, 0, stream>>>(attn, WpT, b_proj, out, M, NE, NE);
}